// Round 1
// baseline (1361.472 us; speedup 1.0000x reference)
//
#include <hip/hip_runtime.h>

// Quadtree attention forward, 3 levels. B=4, C=128, nh=8, d=16, topks=(16,8,8).
// Level shapes: coarse 32x32 (q2), mid 64x64 (q1), fine 128x128 (q0).
// msg2 + combine fused into the fine kernel (final top-k is dead code in ref).

#define DEV static __device__ __forceinline__

DEV float wave_max(float v){
  #pragma unroll
  for(int o=32;o>0;o>>=1) v = fmaxf(v, __shfl_xor(v,o,64));
  return v;
}
DEV float wave_sum(float v){
  #pragma unroll
  for(int o=32;o>0;o>>=1) v += __shfl_xor(v,o,64);
  return v;
}
// all-lanes argmax; ties -> lowest idx (matches jax.lax.top_k)
DEV void wave_argmax(float& v, int& idx){
  #pragma unroll
  for(int o=32;o>0;o>>=1){
    float ov = __shfl_xor(v,o,64);
    int   oi = __shfl_xor(idx,o,64);
    if (ov > v || (ov == v && oi < idx)) { v = ov; idx = oi; }
  }
}

// ---------------- coarse: full attention over S=1024, top-16 ----------------
// grid = B*8*1024 blocks (bid = bh*1024 + l0), 64 threads (one wave).
__global__ __launch_bounds__(64) void k_coarse(
    const float* __restrict__ q, const float* __restrict__ k, const float* __restrict__ v,
    float* __restrict__ msg0, int* __restrict__ topk0)
{
  const int bid = blockIdx.x;
  const int l0  = bid & 1023;
  const int bh  = bid >> 10;        // b*8 + h
  const int lane = threadIdx.x;

  const float* qb = q + (size_t)bh*16*1024;
  const float* kb = k + (size_t)bh*16*1024;
  const float* vb = v + (size_t)bh*16*1024;

  float qv[16];
  #pragma unroll
  for(int dd=0;dd<16;dd++) qv[dd] = qb[dd*1024 + l0];

  // scores: lane owns s = j*64+lane, j=0..15
  float sc[16]; float m = -1e30f;
  #pragma unroll
  for(int j=0;j<16;j++){
    const int s = j*64 + lane;
    float a = 0.f;
    #pragma unroll
    for(int dd=0;dd<16;dd++) a = fmaf(qv[dd], kb[dd*1024 + s], a);
    a *= 0.25f;            // d^-0.5, d=16
    sc[j] = a;
    m = fmaxf(m, a);
  }
  m = wave_max(m);

  float e[16]; float lsum = 0.f;
  #pragma unroll
  for(int j=0;j<16;j++){ e[j] = __expf(sc[j]-m); lsum += e[j]; }
  lsum = wave_sum(lsum);
  const float inv = 1.0f/lsum;

  // msg0 = A @ V
  float acc[16];
  #pragma unroll
  for(int dd=0;dd<16;dd++) acc[dd]=0.f;
  #pragma unroll
  for(int j=0;j<16;j++){
    const int s = j*64 + lane;
    const float ej = e[j];
    #pragma unroll
    for(int dd=0;dd<16;dd++) acc[dd] = fmaf(ej, vb[dd*1024 + s], acc[dd]);
  }
  #pragma unroll
  for(int dd=0;dd<16;dd++) acc[dd] = wave_sum(acc[dd]);
  {
    float val = 0.f;
    #pragma unroll
    for(int dd=0;dd<16;dd++) if ((lane&15)==dd) val = acc[dd];
    if (lane < 16) msg0[(size_t)bid*16 + lane] = val*inv;
  }

  // top-16 by score (== top-16 of A), descending, ties -> lowest s
  int cap = 0;
  for(int r=0;r<16;r++){
    float bv = sc[0]; int bj = 0;
    #pragma unroll
    for(int j=1;j<16;j++) if (sc[j] > bv){ bv = sc[j]; bj = j; }   // lowest j on tie
    int bidx = bj*64 + lane;
    wave_argmax(bv, bidx);
    if (lane == (bidx & 63)){
      const int wj = bidx >> 6;
      #pragma unroll
      for(int j=0;j<16;j++) if (j==wj) sc[j] = -1e30f;
    }
    if (lane == r) cap = bidx;
  }
  if (lane < 16) topk0[(size_t)bid*16 + lane] = cap;
}

// ---------------- mid: K=64 gathered children, 4 queries/group, top-8 -------
// grid = B*8*1024 (bid = bh*1024 + l), 64 threads; lane = gathered key.
__global__ __launch_bounds__(64) void k_mid(
    const float* __restrict__ q, const float* __restrict__ k, const float* __restrict__ v,
    const int* __restrict__ topk0, float* __restrict__ msg1, int* __restrict__ topk1)
{
  const int bid = blockIdx.x;
  const int l   = bid & 1023;
  const int bh  = bid >> 10;
  const int gy = l >> 5, gx = l & 31;
  const int lane = threadIdx.x;

  // gathered key: winner rank w, child c=(x,y); pos in 64x64 grid
  const int w = lane >> 2, c = lane & 3;
  const int widx = topk0[(size_t)bid*16 + w];
  const int ty = widx >> 5, tx = widx & 31;
  const int pos = (2*ty + (c>>1))*64 + (2*tx + (c&1));

  const float* qb = q + (size_t)bh*16*4096;
  const float* kb = k + (size_t)bh*16*4096;
  const float* vb = v + (size_t)bh*16*4096;

  float kv[16];
  #pragma unroll
  for(int dd=0;dd<16;dd++) kv[dd] = kb[dd*4096 + pos];

  float sc[4];
  #pragma unroll
  for(int t=0;t<4;t++){
    const int qp = (2*gy + (t>>1))*64 + (2*gx + (t&1));
    float a = 0.f;
    #pragma unroll
    for(int dd=0;dd<16;dd++) a = fmaf(qb[dd*4096 + qp], kv[dd], a);
    sc[t] = a*0.25f;
  }

  __shared__ float s_e[4][64];
  __shared__ float s_v[64][16];

  float e[4];
  #pragma unroll
  for(int t=0;t<4;t++){
    float m = wave_max(sc[t]);
    e[t] = __expf(sc[t]-m);
    float lsum = wave_sum(e[t]);
    s_e[t][lane] = e[t] / lsum;       // A
  }
  #pragma unroll
  for(int dd=0;dd<16;dd++) s_v[lane][dd] = vb[dd*4096 + pos];
  __syncthreads();

  // msg1: lane = (t,dd)
  {
    const int t = lane >> 4, dd = lane & 15;
    float a = 0.f;
    #pragma unroll
    for(int kk=0;kk<64;kk++) a = fmaf(s_e[t][kk], s_v[kk][dd], a);
    const int sp = (2*gy + (t>>1))*64 + (2*gx + (t&1));
    msg1[((size_t)bh*4096 + sp)*16 + dd] = a;
  }

  // top-8 per t over the 64 gathered keys; ties -> lowest gathered index (=lane)
  int cap = 0;
  #pragma unroll
  for(int t=0;t<4;t++){
    float ev = e[t];
    for(int r=0;r<8;r++){
      float bv = ev; int bidx = lane;
      wave_argmax(bv, bidx);
      const int wpos = __shfl(pos, bidx, 64);   // absolute position of winner
      if (lane == bidx) ev = -1e30f;
      if (lane == t*16 + r) cap = wpos;
    }
  }
  {
    const int t = lane >> 4, r = lane & 15;
    if (r < 8){
      const int sp = (2*gy + (t>>1))*64 + (2*gx + (t&1));
      topk1[((size_t)bh*4096 + sp)*8 + r] = cap;
    }
  }
}

// ---------------- fine: K=32 gathered children + fused combine --------------
// grid = B*8*4096 (bid = bh*4096 + l), 64 threads; lanes 0..31 = keys.
__global__ __launch_bounds__(64) void k_fine(
    const float* __restrict__ q, const float* __restrict__ k, const float* __restrict__ v,
    const int* __restrict__ topk1, const float* __restrict__ msg0,
    const float* __restrict__ msg1, const float* __restrict__ wvec,
    float* __restrict__ out)
{
  const int bid = blockIdx.x;
  const int l   = bid & 4095;
  const int bh  = bid >> 12;
  const int b = bh >> 3, h = bh & 7;
  const int gy = l >> 6, gx = l & 63;
  const int lane = threadIdx.x;

  const float* qb = q + (size_t)bh*16*16384;
  const float* kb = k + (size_t)bh*16*16384;
  const float* vb = v + (size_t)bh*16*16384;

  __shared__ float s_e[4][32];
  __shared__ float s_v[32][16];

  float sc[4];
  if (lane < 32){
    const int w = lane >> 2, c = lane & 3;
    const int widx = topk1[(size_t)bid*8 + w];
    const int ty = widx >> 6, tx = widx & 63;
    const int pos = (2*ty + (c>>1))*128 + (2*tx + (c&1));
    float kv[16];
    #pragma unroll
    for(int dd=0;dd<16;dd++) kv[dd] = kb[dd*16384 + pos];
    #pragma unroll
    for(int t=0;t<4;t++){
      const int qp = (2*gy + (t>>1))*128 + (2*gx + (t&1));
      float a = 0.f;
      #pragma unroll
      for(int dd=0;dd<16;dd++) a = fmaf(qb[dd*16384 + qp], kv[dd], a);
      sc[t] = a*0.25f;
    }
    #pragma unroll
    for(int dd=0;dd<16;dd++) s_v[lane][dd] = vb[dd*16384 + pos];
  } else {
    #pragma unroll
    for(int t=0;t<4;t++) sc[t] = -1e30f;   // exp -> 0, doesn't affect max/sum
  }

  #pragma unroll
  for(int t=0;t<4;t++){
    const float m = wave_max(sc[t]);
    const float e = __expf(sc[t]-m);
    const float lsum = wave_sum(e);
    if (lane < 32) s_e[t][lane] = e / lsum;
  }
  __syncthreads();

  // weight softmax (3 scalars)
  const float w0i = wvec[0], w1i = wvec[1], w2i = wvec[2];
  const float wm = fmaxf(w0i, fmaxf(w1i, w2i));
  float e0 = __expf(w0i-wm), e1 = __expf(w1i-wm), e2 = __expf(w2i-wm);
  const float wsum = e0+e1+e2;
  e0/=wsum; e1/=wsum; e2/=wsum;

  // msg2 + combine: lane = (t,dd)
  const int t = lane >> 4, dd = lane & 15;
  float a = 0.f;
  #pragma unroll
  for(int kk=0;kk<32;kk++) a = fmaf(s_e[t][kk], s_v[kk][dd], a);

  const int cl = (gy>>1)*32 + (gx>>1);                 // coarse ancestor token
  const float m0 = msg0[((size_t)bh*1024 + cl)*16 + dd];
  const float m1 = msg1[(size_t)bid*16 + dd];          // mid token == group id l
  const int p = (2*gy + (t>>1))*128 + (2*gx + (t&1));  // fine spatial position
  out[(((size_t)b*16384 + p)*8 + h)*16 + dd] = e0*m0 + e1*m1 + e2*a;
}

extern "C" void kernel_launch(void* const* d_in, const int* in_sizes, int n_in,
                              void* d_out, int out_size, void* d_ws, size_t ws_size,
                              hipStream_t stream) {
  const float* q0 = (const float*)d_in[0];
  const float* q1 = (const float*)d_in[1];
  const float* q2 = (const float*)d_in[2];
  const float* k0 = (const float*)d_in[3];
  const float* k1 = (const float*)d_in[4];
  const float* k2 = (const float*)d_in[5];
  const float* v0 = (const float*)d_in[6];
  const float* v1 = (const float*)d_in[7];
  const float* v2 = (const float*)d_in[8];
  const float* wv = (const float*)d_in[9];
  float* out = (float*)d_out;

  // workspace layout (16 MB total)
  float* msg0  = (float*)d_ws;                 // [B*8][1024][16]
  int*   topk0 = (int*)(msg0 + 524288);        // [B*8][1024][16]
  float* msg1  = (float*)(topk0 + 524288);     // [B*8][4096][16]
  int*   topk1 = (int*)(msg1 + 2097152);       // [B*8][4096][8]

  hipLaunchKernelGGL(k_coarse, dim3(32768), dim3(64), 0, stream, q2, k2, v2, msg0, topk0);
  hipLaunchKernelGGL(k_mid,    dim3(32768), dim3(64), 0, stream, q1, k1, v1, topk0, msg1, topk1);
  hipLaunchKernelGGL(k_fine,   dim3(131072), dim3(64), 0, stream, q0, k0, v0, topk1, msg0, msg1, wv, out);
}

// Round 2
// 988.550 us; speedup vs baseline: 1.3772x; 1.3772x over previous
//
#include <hip/hip_runtime.h>

// Quadtree attention forward, 3 levels. B=4, C=128, nh=8, d=16, topks=(16,8,8).
// Round 2: float4-coalesced coarse K/V loads, 4-wave blocks everywhere,
// tree-scan top-k. msg2 + combine fused into fine kernel.

#define DEV static __device__ __forceinline__

DEV float wave_max(float v){
  #pragma unroll
  for(int o=32;o>0;o>>=1) v = fmaxf(v, __shfl_xor(v,o,64));
  return v;
}
DEV float wave_sum(float v){
  #pragma unroll
  for(int o=32;o>0;o>>=1) v += __shfl_xor(v,o,64);
  return v;
}
// all-lanes argmax; ties -> lowest idx (matches jax.lax.top_k)
DEV void wave_argmax(float& v, int& idx){
  #pragma unroll
  for(int o=32;o>0;o>>=1){
    float ov = __shfl_xor(v,o,64);
    int   oi = __shfl_xor(idx,o,64);
    if (ov > v || (ov == v && oi < idx)) { v = ov; idx = oi; }
  }
}

// ---------------- coarse: full attention over S=1024, top-16 ----------------
// 256 thr = 4 waves, 1 query/wave. slot = blockIdx.x*4 + wave = bh*1024 + l0.
// Lane owns s = g*256 + lane*4 + e  (g,e in 0..3) -> K/V loads are float4,
// consecutive lanes 16B apart: perfectly coalesced 1KB per instruction.
__global__ __launch_bounds__(256,4) void k_coarse(
    const float* __restrict__ q, const float* __restrict__ k, const float* __restrict__ v,
    float* __restrict__ msg0, int* __restrict__ topk0)
{
  const int slot = blockIdx.x*4 + (threadIdx.x>>6);
  const int l0  = slot & 1023;
  const int bh  = slot >> 10;
  const int lane = threadIdx.x & 63;

  const float* qb = q + (size_t)bh*16*1024;
  const float* kb = k + (size_t)bh*16*1024;
  const float* vb = v + (size_t)bh*16*1024;

  float qv[16];
  #pragma unroll
  for(int dd=0;dd<16;dd++) qv[dd] = qb[dd*1024 + l0];   // wave-uniform -> s_load

  // scores
  float sc[16];
  #pragma unroll
  for(int j=0;j<16;j++) sc[j] = 0.f;
  #pragma unroll
  for(int dd=0;dd<16;dd++){
    const float4* kp = (const float4*)(kb + dd*1024 + lane*4);
    float4 kg0 = kp[0], kg1 = kp[64], kg2 = kp[128], kg3 = kp[192]; // g*256/4
    const float qd = qv[dd];
    sc[ 0]=fmaf(qd,kg0.x,sc[ 0]); sc[ 1]=fmaf(qd,kg0.y,sc[ 1]);
    sc[ 2]=fmaf(qd,kg0.z,sc[ 2]); sc[ 3]=fmaf(qd,kg0.w,sc[ 3]);
    sc[ 4]=fmaf(qd,kg1.x,sc[ 4]); sc[ 5]=fmaf(qd,kg1.y,sc[ 5]);
    sc[ 6]=fmaf(qd,kg1.z,sc[ 6]); sc[ 7]=fmaf(qd,kg1.w,sc[ 7]);
    sc[ 8]=fmaf(qd,kg2.x,sc[ 8]); sc[ 9]=fmaf(qd,kg2.y,sc[ 9]);
    sc[10]=fmaf(qd,kg2.z,sc[10]); sc[11]=fmaf(qd,kg2.w,sc[11]);
    sc[12]=fmaf(qd,kg3.x,sc[12]); sc[13]=fmaf(qd,kg3.y,sc[13]);
    sc[14]=fmaf(qd,kg3.z,sc[14]); sc[15]=fmaf(qd,kg3.w,sc[15]);
  }
  float m = -1e30f;
  #pragma unroll
  for(int j=0;j<16;j++){ sc[j] *= 0.25f; m = fmaxf(m, sc[j]); }
  m = wave_max(m);

  float p[16]; float lsum = 0.f;
  #pragma unroll
  for(int j=0;j<16;j++){ p[j] = __expf(sc[j]-m); lsum += p[j]; }
  lsum = wave_sum(lsum);
  const float inv = 1.0f/lsum;
  #pragma unroll
  for(int j=0;j<16;j++) p[j] *= inv;

  // msg0 = A @ V
  float acc[16];
  #pragma unroll
  for(int dd=0;dd<16;dd++){
    const float4* vp = (const float4*)(vb + dd*1024 + lane*4);
    float4 vg0 = vp[0], vg1 = vp[64], vg2 = vp[128], vg3 = vp[192];
    float a;
    a  = p[ 0]*vg0.x; a = fmaf(p[ 1],vg0.y,a); a = fmaf(p[ 2],vg0.z,a); a = fmaf(p[ 3],vg0.w,a);
    a  = fmaf(p[ 4],vg1.x,a); a = fmaf(p[ 5],vg1.y,a); a = fmaf(p[ 6],vg1.z,a); a = fmaf(p[ 7],vg1.w,a);
    a  = fmaf(p[ 8],vg2.x,a); a = fmaf(p[ 9],vg2.y,a); a = fmaf(p[10],vg2.z,a); a = fmaf(p[11],vg2.w,a);
    a  = fmaf(p[12],vg3.x,a); a = fmaf(p[13],vg3.y,a); a = fmaf(p[14],vg3.z,a); a = fmaf(p[15],vg3.w,a);
    acc[dd] = a;
  }
  #pragma unroll
  for(int dd=0;dd<16;dd++) acc[dd] = wave_sum(acc[dd]);
  {
    float val = 0.f;
    #pragma unroll
    for(int dd=0;dd<16;dd++) if ((lane&15)==dd) val = acc[dd];
    if (lane < 16) msg0[(size_t)slot*16 + lane] = val;
  }

  // top-16 by score, descending, ties -> lowest s.  s = (j>>2)*256 + lane*4 + (j&3)
  int cap = 0;
  for(int r=0;r<16;r++){
    float bv[16]; int bs[16];
    #pragma unroll
    for(int j=0;j<16;j++){ bv[j] = sc[j]; bs[j] = (j>>2)*256 + lane*4 + (j&3); }
    #pragma unroll
    for(int st=8; st>=1; st>>=1)
      #pragma unroll
      for(int i=0;i<8;i++) if (i<st){
        if (bv[i+st] > bv[i]) { bv[i]=bv[i+st]; bs[i]=bs[i+st]; }  // tie keeps lower s
      }
    float wv_ = bv[0]; int ws_ = bs[0];
    wave_argmax(wv_, ws_);
    const bool mine = (((ws_>>2)&63) == lane);
    const int wj = ((ws_>>8)<<2) | (ws_&3);
    #pragma unroll
    for(int j=0;j<16;j++) if (mine && j==wj) sc[j] = -1e30f;
    if (lane == r) cap = ws_;
  }
  if (lane < 16) topk0[(size_t)slot*16 + lane] = cap;
}

// ---------------- mid: K=64 gathered children, 4 queries/group, top-8 -------
// 256 thr = 4 waves, 1 group/wave; lane = gathered key.
__global__ __launch_bounds__(256,8) void k_mid(
    const float* __restrict__ q, const float* __restrict__ k, const float* __restrict__ v,
    const int* __restrict__ topk0, float* __restrict__ msg1, int* __restrict__ topk1)
{
  const int wid = threadIdx.x >> 6;
  const int slot = blockIdx.x*4 + wid;
  const int l   = slot & 1023;
  const int bh  = slot >> 10;
  const int gy = l >> 5, gx = l & 31;
  const int lane = threadIdx.x & 63;

  // gathered key: winner rank w, child c=(cy,cx); pos in 64x64 grid
  const int w = lane >> 2, c = lane & 3;
  const int widx = topk0[(size_t)slot*16 + w];
  const int ty = widx >> 5, tx = widx & 31;
  const int pos = (2*ty + (c>>1))*64 + (2*tx + (c&1));

  const float* qb = q + (size_t)bh*16*4096;
  const float* kb = k + (size_t)bh*16*4096;
  const float* vb = v + (size_t)bh*16*4096;

  float kv[16];
  #pragma unroll
  for(int dd=0;dd<16;dd++) kv[dd] = kb[dd*4096 + pos];

  float sc[4];
  #pragma unroll
  for(int t=0;t<4;t++){
    const int qp = (2*gy + (t>>1))*64 + (2*gx + (t&1));
    float a = 0.f;
    #pragma unroll
    for(int dd=0;dd<16;dd++) a = fmaf(qb[dd*4096 + qp], kv[dd], a);
    sc[t] = a*0.25f;
  }

  __shared__ float s_e[4][4][64];
  __shared__ float s_v[4][64][16];

  float e[4];
  #pragma unroll
  for(int t=0;t<4;t++){
    float m = wave_max(sc[t]);
    e[t] = __expf(sc[t]-m);
    float lsum = wave_sum(e[t]);
    s_e[wid][t][lane] = e[t] / lsum;       // A
  }
  #pragma unroll
  for(int dd=0;dd<16;dd++) s_v[wid][lane][dd] = vb[dd*4096 + pos];
  __syncthreads();

  // msg1: lane = (t,dd)
  {
    const int t = lane >> 4, dd = lane & 15;
    float a = 0.f;
    #pragma unroll
    for(int kk=0;kk<64;kk++) a = fmaf(s_e[wid][t][kk], s_v[wid][kk][dd], a);
    const int sp = (2*gy + (t>>1))*64 + (2*gx + (t&1));
    msg1[((size_t)bh*4096 + sp)*16 + dd] = a;
  }

  // top-8 per t over the 64 gathered keys; ties -> lowest gathered index (=lane)
  int cap = 0;
  #pragma unroll
  for(int t=0;t<4;t++){
    float ev = e[t];
    for(int r=0;r<8;r++){
      float bv = ev; int bidx = lane;
      wave_argmax(bv, bidx);
      const int wpos = __shfl(pos, bidx, 64);   // absolute position of winner
      if (lane == bidx) ev = -1e30f;
      if (lane == t*16 + r) cap = wpos;
    }
  }
  {
    const int t = lane >> 4, r = lane & 15;
    if (r < 8){
      const int sp = (2*gy + (t>>1))*64 + (2*gx + (t&1));
      topk1[((size_t)bh*4096 + sp)*8 + r] = cap;
    }
  }
}

// ---------------- fine: K=32 gathered children + fused combine --------------
// 256 thr = 4 waves, 1 group/wave; lanes 0..31 = keys.
__global__ __launch_bounds__(256,8) void k_fine(
    const float* __restrict__ q, const float* __restrict__ k, const float* __restrict__ v,
    const int* __restrict__ topk1, const float* __restrict__ msg0,
    const float* __restrict__ msg1, const float* __restrict__ wvec,
    float* __restrict__ out)
{
  const int wid = threadIdx.x >> 6;
  const int slot = blockIdx.x*4 + wid;
  const int l   = slot & 4095;
  const int bh  = slot >> 12;
  const int b = bh >> 3, h = bh & 7;
  const int gy = l >> 6, gx = l & 63;
  const int lane = threadIdx.x & 63;

  const float* qb = q + (size_t)bh*16*16384;
  const float* kb = k + (size_t)bh*16*16384;
  const float* vb = v + (size_t)bh*16*16384;

  __shared__ float s_e[4][4][32];
  __shared__ float s_v[4][32][16];

  float sc[4];
  if (lane < 32){
    const int w = lane >> 2, c = lane & 3;
    const int widx = topk1[(size_t)slot*8 + w];
    const int ty = widx >> 6, tx = widx & 63;
    const int pos = (2*ty + (c>>1))*128 + (2*tx + (c&1));
    float kv[16];
    #pragma unroll
    for(int dd=0;dd<16;dd++) kv[dd] = kb[dd*16384 + pos];
    #pragma unroll
    for(int t=0;t<4;t++){
      const int qp = (2*gy + (t>>1))*128 + (2*gx + (t&1));
      float a = 0.f;
      #pragma unroll
      for(int dd=0;dd<16;dd++) a = fmaf(qb[dd*16384 + qp], kv[dd], a);
      sc[t] = a*0.25f;
    }
    #pragma unroll
    for(int dd=0;dd<16;dd++) s_v[wid][lane][dd] = vb[dd*16384 + pos];
  } else {
    #pragma unroll
    for(int t=0;t<4;t++) sc[t] = -1e30f;   // exp -> 0, doesn't affect max/sum
  }

  #pragma unroll
  for(int t=0;t<4;t++){
    const float m = wave_max(sc[t]);
    const float e = __expf(sc[t]-m);
    const float lsum = wave_sum(e);
    if (lane < 32) s_e[wid][t][lane] = e / lsum;
  }
  __syncthreads();

  // weight softmax (3 scalars)
  const float w0i = wvec[0], w1i = wvec[1], w2i = wvec[2];
  const float wm = fmaxf(w0i, fmaxf(w1i, w2i));
  float e0 = __expf(w0i-wm), e1 = __expf(w1i-wm), e2 = __expf(w2i-wm);
  const float wsum = e0+e1+e2;
  e0/=wsum; e1/=wsum; e2/=wsum;

  // msg2 + combine: lane = (t,dd)
  const int t = lane >> 4, dd = lane & 15;
  float a = 0.f;
  #pragma unroll
  for(int kk=0;kk<32;kk++) a = fmaf(s_e[wid][t][kk], s_v[wid][kk][dd], a);

  const int cl = (gy>>1)*32 + (gx>>1);                 // coarse ancestor token
  const float m0 = msg0[((size_t)bh*1024 + cl)*16 + dd];
  const float m1 = msg1[(size_t)slot*16 + dd];         // mid token == group id l
  const int p = (2*gy + (t>>1))*128 + (2*gx + (t&1));  // fine spatial position
  out[(((size_t)b*16384 + p)*8 + h)*16 + dd] = e0*m0 + e1*m1 + e2*a;
}

extern "C" void kernel_launch(void* const* d_in, const int* in_sizes, int n_in,
                              void* d_out, int out_size, void* d_ws, size_t ws_size,
                              hipStream_t stream) {
  const float* q0 = (const float*)d_in[0];
  const float* q1 = (const float*)d_in[1];
  const float* q2 = (const float*)d_in[2];
  const float* k0 = (const float*)d_in[3];
  const float* k1 = (const float*)d_in[4];
  const float* k2 = (const float*)d_in[5];
  const float* v0 = (const float*)d_in[6];
  const float* v1 = (const float*)d_in[7];
  const float* v2 = (const float*)d_in[8];
  const float* wv = (const float*)d_in[9];
  float* out = (float*)d_out;

  // workspace layout (16 MB total)
  float* msg0  = (float*)d_ws;                 // [B*8][1024][16]
  int*   topk0 = (int*)(msg0 + 524288);        // [B*8][1024][16]
  float* msg1  = (float*)(topk0 + 524288);     // [B*8][4096][16]
  int*   topk1 = (int*)(msg1 + 2097152);       // [B*8][4096][8]

  hipLaunchKernelGGL(k_coarse, dim3(8192),  dim3(256), 0, stream, q2, k2, v2, msg0, topk0);
  hipLaunchKernelGGL(k_mid,    dim3(8192),  dim3(256), 0, stream, q1, k1, v1, topk0, msg1, topk1);
  hipLaunchKernelGGL(k_fine,   dim3(32768), dim3(256), 0, stream, q0, k0, v0, topk1, msg0, msg1, wv, out);
}

// Round 3
// 863.878 us; speedup vs baseline: 1.5760x; 1.1443x over previous
//
#include <hip/hip_runtime.h>

// Quadtree attention forward, 3 levels. B=4, C=128, nh=8, d=16, topks=(16,8,8).
// Round 3: all-lane float2 gathers into conflict-free LDS (mid/fine, no barriers,
// wave-private LDS), coarse LDS-tiled K/V shared across 8 queries/block.

#define DEV static __device__ __forceinline__

DEV float wave_max(float v){
  #pragma unroll
  for(int o=32;o>0;o>>=1) v = fmaxf(v, __shfl_xor(v,o,64));
  return v;
}
DEV float wave_sum(float v){
  #pragma unroll
  for(int o=32;o>0;o>>=1) v += __shfl_xor(v,o,64);
  return v;
}
DEV float half_max(float v){           // reduce within aligned 32-lane half
  #pragma unroll
  for(int o=16;o>0;o>>=1) v = fmaxf(v, __shfl_xor(v,o,64));
  return v;
}
DEV float half_sum(float v){
  #pragma unroll
  for(int o=16;o>0;o>>=1) v += __shfl_xor(v,o,64);
  return v;
}
// all-lanes argmax; ties -> lowest idx (matches jax.lax.top_k)
DEV void wave_argmax(float& v, int& idx){
  #pragma unroll
  for(int o=32;o>0;o>>=1){
    float ov = __shfl_xor(v,o,64);
    int   oi = __shfl_xor(idx,o,64);
    if (ov > v || (ov == v && oi < idx)) { v = ov; idx = oi; }
  }
}

// top-16 of 1024 scores, wave-distributed: lane holds sc[j] for
// s = (j>>2)*256 + lane*4 + (j&3). Destroys sc. Returns cap (lane r holds rank r).
DEV int top16_1024(float (&sc)[16], int lane){
  int cap = 0;
  for(int r=0;r<16;r++){
    float bv[16]; int bs[16];
    #pragma unroll
    for(int j=0;j<16;j++){ bv[j] = sc[j]; bs[j] = (j>>2)*256 + lane*4 + (j&3); }
    #pragma unroll
    for(int st=8; st>=1; st>>=1)
      #pragma unroll
      for(int i=0;i<st;i++)
        if (bv[i+st] > bv[i]) { bv[i]=bv[i+st]; bs[i]=bs[i+st]; }  // tie keeps lower s
    float wv_ = bv[0]; int ws_ = bs[0];
    wave_argmax(wv_, ws_);
    const bool mine = (((ws_>>2)&63) == lane);
    const int wj = ((ws_>>8)<<2) | (ws_&3);
    #pragma unroll
    for(int j=0;j<16;j++) if (mine && j==wj) sc[j] = -1e30f;
    if (lane == r) cap = ws_;
  }
  return cap;
}

// ---------------- coarse: full attention over S=1024, top-16 ----------------
// 256 thr = 4 waves; 2 queries/wave (8/block, same bh). K and V streamed
// through a shared 16KB LDS tile in 4 chunks of 256 tokens.
__global__ __launch_bounds__(256) void k_coarse(
    const float* __restrict__ q, const float* __restrict__ k, const float* __restrict__ v,
    float* __restrict__ msg0, int* __restrict__ topk0)
{
  __shared__ float4 s_t[16*64];      // [dd][64 float4] = 16KB
  const int tid = threadIdx.x, wid = tid>>6, lane = tid&63;
  const int gq0 = __builtin_amdgcn_readfirstlane(blockIdx.x*8 + wid*2);
  const int bh = gq0 >> 10, l0 = gq0 & 1023;

  const float* qb = q + (size_t)bh*16384;
  const float* kb = k + (size_t)bh*16384;
  const float* vb = v + (size_t)bh*16384;

  float qv0[16], qv1[16];
  #pragma unroll
  for(int dd=0;dd<16;dd++){ qv0[dd]=qb[dd*1024+l0]; qv1[dd]=qb[dd*1024+l0+1]; }

  float p0[16], p1[16];
  #pragma unroll
  for(int j=0;j<16;j++){ p0[j]=0.f; p1[j]=0.f; }

  // ---- K pass: scores ----
  #pragma unroll
  for(int c=0;c<4;c++){
    __syncthreads();
    #pragma unroll
    for(int i=0;i<4;i++){
      const int f = tid + i*256, dd = f>>6, g = f&63;
      s_t[f] = ((const float4*)(kb + dd*1024 + c*256))[g];
    }
    __syncthreads();
    #pragma unroll
    for(int dd=0;dd<16;dd++){
      const float4 kf = s_t[dd*64 + lane];
      p0[c*4+0]=fmaf(qv0[dd],kf.x,p0[c*4+0]); p0[c*4+1]=fmaf(qv0[dd],kf.y,p0[c*4+1]);
      p0[c*4+2]=fmaf(qv0[dd],kf.z,p0[c*4+2]); p0[c*4+3]=fmaf(qv0[dd],kf.w,p0[c*4+3]);
      p1[c*4+0]=fmaf(qv1[dd],kf.x,p1[c*4+0]); p1[c*4+1]=fmaf(qv1[dd],kf.y,p1[c*4+1]);
      p1[c*4+2]=fmaf(qv1[dd],kf.z,p1[c*4+2]); p1[c*4+3]=fmaf(qv1[dd],kf.w,p1[c*4+3]);
    }
  }

  // ---- softmax (normalized probs; order-preserving for top-k) ----
  float m0=-1e30f, m1=-1e30f;
  #pragma unroll
  for(int j=0;j<16;j++){ p0[j]*=0.25f; p1[j]*=0.25f; m0=fmaxf(m0,p0[j]); m1=fmaxf(m1,p1[j]); }
  m0 = wave_max(m0); m1 = wave_max(m1);
  float s0=0.f, s1=0.f;
  #pragma unroll
  for(int j=0;j<16;j++){ p0[j]=__expf(p0[j]-m0); p1[j]=__expf(p1[j]-m1); s0+=p0[j]; s1+=p1[j]; }
  s0 = wave_sum(s0); s1 = wave_sum(s1);
  const float i0=1.0f/s0, i1=1.0f/s1;
  #pragma unroll
  for(int j=0;j<16;j++){ p0[j]*=i0; p1[j]*=i1; }

  // ---- V pass: msg = A @ V ----
  float a0[16], a1[16];
  #pragma unroll
  for(int dd=0;dd<16;dd++){ a0[dd]=0.f; a1[dd]=0.f; }
  #pragma unroll
  for(int c=0;c<4;c++){
    __syncthreads();
    #pragma unroll
    for(int i=0;i<4;i++){
      const int f = tid + i*256, dd = f>>6, g = f&63;
      s_t[f] = ((const float4*)(vb + dd*1024 + c*256))[g];
    }
    __syncthreads();
    #pragma unroll
    for(int dd=0;dd<16;dd++){
      const float4 vf = s_t[dd*64 + lane];
      a0[dd]=fmaf(p0[c*4+0],vf.x,a0[dd]); a0[dd]=fmaf(p0[c*4+1],vf.y,a0[dd]);
      a0[dd]=fmaf(p0[c*4+2],vf.z,a0[dd]); a0[dd]=fmaf(p0[c*4+3],vf.w,a0[dd]);
      a1[dd]=fmaf(p1[c*4+0],vf.x,a1[dd]); a1[dd]=fmaf(p1[c*4+1],vf.y,a1[dd]);
      a1[dd]=fmaf(p1[c*4+2],vf.z,a1[dd]); a1[dd]=fmaf(p1[c*4+3],vf.w,a1[dd]);
    }
  }
  #pragma unroll
  for(int dd=0;dd<16;dd++){ a0[dd]=wave_sum(a0[dd]); a1[dd]=wave_sum(a1[dd]); }
  {
    float val = 0.f;
    #pragma unroll
    for(int dd=0;dd<16;dd++){
      val = (lane==dd)    ? a0[dd] : val;
      val = (lane==16+dd) ? a1[dd] : val;
    }
    if (lane < 32) msg0[(size_t)(gq0 + (lane>>4))*16 + (lane&15)] = val;
  }

  // ---- top-16 per query ----
  const int c0 = top16_1024(p0, lane);
  if (lane < 16) topk0[(size_t)gq0*16 + lane] = c0;
  const int c1 = top16_1024(p1, lane);
  if (lane < 16) topk0[(size_t)(gq0+1)*16 + lane] = c1;
}

// ---------------- mid: K=64 gathered children, 4 queries/group, top-8 -------
// 256 thr = 4 waves, 1 group/wave, wave-private LDS (no barriers).
// Gather: 64 lanes = 16 winners x 2 rows x {K,V}; each lane 16 float2 loads.
__global__ __launch_bounds__(256) void k_mid(
    const float* __restrict__ q, const float* __restrict__ k, const float* __restrict__ v,
    const int* __restrict__ topk0, float* __restrict__ msg1, int* __restrict__ topk1)
{
  __shared__ float s_k[4][16][66];   // [wid][dd][key] pad 2 -> f2-aligned, conflict-free
  __shared__ float s_v[4][16][66];
  __shared__ float s_e[4][4][65];
  const int tid = threadIdx.x, wid = tid>>6, lane = tid&63;
  const int slot = __builtin_amdgcn_readfirstlane(blockIdx.x*4 + wid);
  const int l = slot & 1023, bh = slot >> 10;
  const int gy = l>>5, gx = l&31;

  const float* qb = q + (size_t)bh*65536;
  const float* kb = k + (size_t)bh*65536;
  const float* vb = v + (size_t)bh*65536;

  // ---- gather K/V children as float2 into LDS ----
  {
    const int kvsel = lane>>5, r = lane&31, w = r>>1, cy = r&1;
    const int widx = topk0[(size_t)slot*16 + w];
    const int ty = widx>>5, tx = widx&31;
    const int base = (2*ty + cy)*64 + 2*tx;
    const float* src = kvsel ? vb : kb;
    float* dst = kvsel ? &s_v[wid][0][0] : &s_k[wid][0][0];
    const int key0 = w*4 + cy*2;
    #pragma unroll
    for(int dd=0;dd<16;dd++){
      const float2 f2 = *(const float2*)(src + dd*4096 + base);
      *(float2*)(dst + dd*66 + key0) = f2;
    }
  }

  // ---- scores: lane = gathered key ----
  float kv[16];
  #pragma unroll
  for(int dd=0;dd<16;dd++) kv[dd] = s_k[wid][dd][lane];
  float p[4];
  #pragma unroll
  for(int t=0;t<4;t++){
    const int qp = (2*gy + (t>>1))*64 + (2*gx + (t&1));
    float a = 0.f;
    #pragma unroll
    for(int dd=0;dd<16;dd++) a = fmaf(qb[dd*4096 + qp], kv[dd], a);
    a *= 0.25f;
    const float m = wave_max(a);
    float e = __expf(a - m);
    const float s = wave_sum(e);
    p[t] = e / s;
    s_e[wid][t][lane] = p[t];
  }

  // ---- top-8 per t over 64 gathered keys (tie -> lowest gathered index) ----
  const int w2 = lane>>2, c2 = lane&3;
  const int widx2 = topk0[(size_t)slot*16 + w2];
  const int pos = (2*(widx2>>5) + (c2>>1))*64 + (2*(widx2&31) + (c2&1));
  int cap = 0;
  #pragma unroll
  for(int t=0;t<4;t++){
    float ev = p[t];
    for(int r8=0;r8<8;r8++){
      float bv = ev; int bidx = lane;
      wave_argmax(bv, bidx);
      const int wpos = __shfl(pos, bidx, 64);
      if (lane == bidx) ev = -1e30f;
      if (lane == t*16 + r8) cap = wpos;
    }
  }
  {
    const int t = lane>>4, rr = lane&15;
    if (rr < 8){
      const int sp = (2*gy + (t>>1))*64 + (2*gx + (t&1));
      topk1[((size_t)bh*4096 + sp)*8 + rr] = cap;
    }
  }

  // ---- msg1 = A @ gathered V: lane = (t,dd) ----
  {
    const int t = lane>>4, dd = lane&15;
    float a = 0.f;
    #pragma unroll
    for(int kk=0;kk<64;kk++) a = fmaf(s_e[wid][t][kk], s_v[wid][dd][kk], a);
    const int sp = (2*gy + (t>>1))*64 + (2*gx + (t&1));
    msg1[((size_t)bh*4096 + sp)*16 + dd] = a;
  }
}

// ---------------- fine: K=32 gathered children + fused combine --------------
// 256 thr = 4 waves, 1 group/wave, wave-private LDS (no barriers).
// Gather: 64 lanes = 8 winners x 2 rows x {K,V} x 2 dd-halves; 8 float2/lane.
__global__ __launch_bounds__(256) void k_fine(
    const float* __restrict__ q, const float* __restrict__ k, const float* __restrict__ v,
    const int* __restrict__ topk1, const float* __restrict__ msg0,
    const float* __restrict__ msg1, const float* __restrict__ wvec,
    float* __restrict__ out)
{
  __shared__ float s_k[4][16][34];
  __shared__ float s_v[4][16][34];
  __shared__ float s_q[4][4][17];
  __shared__ float s_e[4][4][33];
  const int tid = threadIdx.x, wid = tid>>6, lane = tid&63;
  const int slot = __builtin_amdgcn_readfirstlane(blockIdx.x*4 + wid);
  const int l = slot & 4095, bh = slot >> 12;
  const int b = bh>>3, h = bh&7;
  const int gy = l>>6, gx = l&63;

  const float* qb = q + (size_t)bh*262144;
  const float* kb = k + (size_t)bh*262144;
  const float* vb = v + (size_t)bh*262144;

  // ---- stage q: lane = (t,dd), one dword each ----
  {
    const int t = lane>>4, dd = lane&15;
    const int qp = (2*gy + (t>>1))*128 + (2*gx + (t&1));
    s_q[wid][t][dd] = qb[dd*16384 + qp];
  }
  // ---- gather K/V children as float2 into LDS ----
  {
    const int gs = lane>>1, dh = lane&1;
    const int kvsel = gs>>4, r = gs&15, w = r>>1, cy = r&1;
    const int widx = topk1[(size_t)slot*8 + w];
    const int ty = widx>>6, tx = widx&63;
    const int base = (2*ty + cy)*128 + 2*tx;
    const float* src = kvsel ? vb : kb;
    float* dst = kvsel ? &s_v[wid][0][0] : &s_k[wid][0][0];
    const int key0 = w*4 + cy*2;
    #pragma unroll
    for(int j=0;j<8;j++){
      const int dd = dh*8 + j;
      const float2 f2 = *(const float2*)(src + dd*16384 + base);
      *(float2*)(dst + dd*34 + key0) = f2;
    }
  }

  // ---- scores + softmax: lane = (th, key); t = 2*th+tt over 32-lane halves ----
  const int key = lane&31, th = lane>>5;
  float kv[16];
  #pragma unroll
  for(int dd=0;dd<16;dd++) kv[dd] = s_k[wid][dd][key];
  #pragma unroll
  for(int tt=0;tt<2;tt++){
    const int t = th*2 + tt;
    float a = 0.f;
    #pragma unroll
    for(int dd=0;dd<16;dd++) a = fmaf(s_q[wid][t][dd], kv[dd], a);
    a *= 0.25f;
    const float m = half_max(a);
    const float e = __expf(a - m);
    const float s = half_sum(e);
    s_e[wid][t][key] = e / s;
  }

  // ---- weight softmax (3 scalars) ----
  const float w0i = wvec[0], w1i = wvec[1], w2i = wvec[2];
  const float wm = fmaxf(w0i, fmaxf(w1i, w2i));
  float e0 = __expf(w0i-wm), e1 = __expf(w1i-wm), e2 = __expf(w2i-wm);
  const float wsum = e0+e1+e2;
  e0/=wsum; e1/=wsum; e2/=wsum;

  // ---- msg2 + combine: lane = (t,dd) ----
  const int t2 = lane>>4, dd2 = lane&15;
  float a = 0.f;
  #pragma unroll
  for(int kk=0;kk<32;kk++) a = fmaf(s_e[wid][t2][kk], s_v[wid][dd2][kk], a);

  const int cl = (gy>>1)*32 + (gx>>1);
  const float m0 = msg0[((size_t)bh*1024 + cl)*16 + dd2];
  const float m1 = msg1[(size_t)slot*16 + dd2];
  const int pp = (2*gy + (t2>>1))*128 + (2*gx + (t2&1));
  out[(((size_t)b*16384 + pp)*8 + h)*16 + dd2] = e0*m0 + e1*m1 + e2*a;
}

extern "C" void kernel_launch(void* const* d_in, const int* in_sizes, int n_in,
                              void* d_out, int out_size, void* d_ws, size_t ws_size,
                              hipStream_t stream) {
  const float* q0 = (const float*)d_in[0];
  const float* q1 = (const float*)d_in[1];
  const float* q2 = (const float*)d_in[2];
  const float* k0 = (const float*)d_in[3];
  const float* k1 = (const float*)d_in[4];
  const float* k2 = (const float*)d_in[5];
  const float* v0 = (const float*)d_in[6];
  const float* v1 = (const float*)d_in[7];
  const float* v2 = (const float*)d_in[8];
  const float* wv = (const float*)d_in[9];
  float* out = (float*)d_out;

  // workspace layout (16 MB total)
  float* msg0  = (float*)d_ws;                 // [B*8][1024][16]
  int*   topk0 = (int*)(msg0 + 524288);        // [B*8][1024][16]
  float* msg1  = (float*)(topk0 + 524288);     // [B*8][4096][16]
  int*   topk1 = (int*)(msg1 + 2097152);       // [B*8][4096][8]

  hipLaunchKernelGGL(k_coarse, dim3(4096),  dim3(256), 0, stream, q2, k2, v2, msg0, topk0);
  hipLaunchKernelGGL(k_mid,    dim3(8192),  dim3(256), 0, stream, q1, k1, v1, topk0, msg1, topk1);
  hipLaunchKernelGGL(k_fine,   dim3(32768), dim3(256), 0, stream, q0, k0, v0, topk1, msg0, msg1, wv, out);
}

// Round 4
// 575.379 us; speedup vs baseline: 2.3662x; 1.5014x over previous
//
#include <hip/hip_runtime.h>

// Quadtree attention forward, 3 levels. B=4, C=128, nh=8, d=16, topks=(16,8,8).
// Round 4: token-major K/V transpose pre-pass -> every gathered key row = one
// 64B cacheline (4x dwordx4). Coarse = barrier-free two-pass in registers.
// Mid top-8 = 4 parallel 16-lane group selections.

#define DEV static __device__ __forceinline__

DEV float wave_max(float v){
  #pragma unroll
  for(int o=32;o>0;o>>=1) v = fmaxf(v, __shfl_xor(v,o,64));
  return v;
}
DEV float wave_sum(float v){
  #pragma unroll
  for(int o=32;o>0;o>>=1) v += __shfl_xor(v,o,64);
  return v;
}
DEV float half_max(float v){           // aligned 32-lane half
  #pragma unroll
  for(int o=16;o>0;o>>=1) v = fmaxf(v, __shfl_xor(v,o,64));
  return v;
}
DEV float half_sum(float v){
  #pragma unroll
  for(int o=16;o>0;o>>=1) v += __shfl_xor(v,o,64);
  return v;
}
// all-lanes argmax; ties -> lowest idx (matches jax.lax.top_k)
DEV void wave_argmax(float& v, int& idx){
  #pragma unroll
  for(int o=32;o>0;o>>=1){
    float ov = __shfl_xor(v,o,64);
    int   oi = __shfl_xor(idx,o,64);
    if (ov > v || (ov == v && oi < idx)) { v = ov; idx = oi; }
  }
}

// top-16 of 1024 scores; lane holds sc[c] for s = c*64+lane. Destroys sc.
DEV int top16_reg(float (&sc)[16], int lane){
  int cap = 0;
  for(int r=0;r<16;r++){
    float bv[16]; int bj[16];
    #pragma unroll
    for(int j=0;j<16;j++){ bv[j]=sc[j]; bj[j]=j; }
    #pragma unroll
    for(int st=8; st>=1; st>>=1)
      #pragma unroll
      for(int i=0;i<st;i++)
        if (bv[i+st] > bv[i]){ bv[i]=bv[i+st]; bj[i]=bj[i+st]; }  // tie->lower c->lower s
    float wv_ = bv[0]; int ws_ = bj[0]*64 + lane;
    wave_argmax(wv_, ws_);
    const bool mine = ((ws_&63)==lane);
    const int wj = ws_>>6;
    #pragma unroll
    for(int j=0;j<16;j++) if (mine && j==wj) sc[j] = -1e30f;
    if (lane==r) cap = ws_;
  }
  return cap;
}

// -------- transpose [bh][16][S] -> [bh*S][16] (token-major, 64B rows) -------
__global__ __launch_bounds__(256) void k_transpose(
    const float* __restrict__ in, float* __restrict__ out, int lgS)
{
  const int id = blockIdx.x*256 + threadIdx.x;
  const int s = id & ((1<<lgS)-1), bh = id >> lgS;
  const float* src = in + ((size_t)bh<<(lgS+4)) + s;
  float r[16];
  #pragma unroll
  for(int dd=0;dd<16;dd++) r[dd] = src[(size_t)dd<<lgS];
  float4* dst = (float4*)(out + (size_t)id*16);
  dst[0] = make_float4(r[0],r[1],r[2],r[3]);
  dst[1] = make_float4(r[4],r[5],r[6],r[7]);
  dst[2] = make_float4(r[8],r[9],r[10],r[11]);
  dst[3] = make_float4(r[12],r[13],r[14],r[15]);
}

// ---------------- coarse: full attention over S=1024, top-16 ----------------
// 2 queries/wave, no LDS, no barriers. Pass1: scores (K rows), softmax in regs;
// pass2: AV (V rows); then top-16 per query.
template<bool TOK>
__global__ __launch_bounds__(256) void k_coarse(
    const float* __restrict__ q, const float* __restrict__ k, const float* __restrict__ v,
    const float* __restrict__ ktok, const float* __restrict__ vtok,
    float* __restrict__ msg0, int* __restrict__ topk0)
{
  const int tid = threadIdx.x, wid = tid>>6, lane = tid&63;
  const int gq0 = __builtin_amdgcn_readfirstlane((blockIdx.x*4 + wid)*2);
  const int bh = gq0>>10, l0 = gq0&1023;

  const float* qb = q + (size_t)bh*16384;
  float qv0[16], qv1[16];
  #pragma unroll
  for(int dd=0;dd<16;dd++){ qv0[dd]=qb[dd*1024+l0]; qv1[dd]=qb[dd*1024+l0+1]; }

  // ---- pass 1: scores ----
  float sc0[16], sc1[16];
  #pragma unroll
  for(int c=0;c<16;c++){
    const int s = c*64 + lane;
    float kr[16];
    if constexpr (TOK){
      const float4* kp = (const float4*)(ktok + ((size_t)bh*1024 + s)*16);
      float4 x0=kp[0], x1=kp[1], x2=kp[2], x3=kp[3];
      kr[0]=x0.x; kr[1]=x0.y; kr[2]=x0.z; kr[3]=x0.w;
      kr[4]=x1.x; kr[5]=x1.y; kr[6]=x1.z; kr[7]=x1.w;
      kr[8]=x2.x; kr[9]=x2.y; kr[10]=x2.z; kr[11]=x2.w;
      kr[12]=x3.x; kr[13]=x3.y; kr[14]=x3.z; kr[15]=x3.w;
    } else {
      const float* kb = k + (size_t)bh*16384 + s;
      #pragma unroll
      for(int dd=0;dd<16;dd++) kr[dd] = kb[dd*1024];
    }
    float a0=0.f, a1=0.f;
    #pragma unroll
    for(int dd=0;dd<16;dd++){ a0=fmaf(qv0[dd],kr[dd],a0); a1=fmaf(qv1[dd],kr[dd],a1); }
    sc0[c]=a0*0.25f; sc1[c]=a1*0.25f;
  }

  // ---- softmax (normalized in place; order-preserving for top-k) ----
  float m0=-1e30f, m1=-1e30f;
  #pragma unroll
  for(int c=0;c<16;c++){ m0=fmaxf(m0,sc0[c]); m1=fmaxf(m1,sc1[c]); }
  m0 = wave_max(m0); m1 = wave_max(m1);
  float s0=0.f, s1=0.f;
  #pragma unroll
  for(int c=0;c<16;c++){ sc0[c]=__expf(sc0[c]-m0); sc1[c]=__expf(sc1[c]-m1); s0+=sc0[c]; s1+=sc1[c]; }
  s0 = wave_sum(s0); s1 = wave_sum(s1);
  const float i0=1.0f/s0, i1=1.0f/s1;
  #pragma unroll
  for(int c=0;c<16;c++){ sc0[c]*=i0; sc1[c]*=i1; }

  // ---- pass 2: AV ----
  float acc0[16], acc1[16];
  #pragma unroll
  for(int dd=0;dd<16;dd++){ acc0[dd]=0.f; acc1[dd]=0.f; }
  #pragma unroll
  for(int c=0;c<16;c++){
    const int s = c*64 + lane;
    float vr[16];
    if constexpr (TOK){
      const float4* vp = (const float4*)(vtok + ((size_t)bh*1024 + s)*16);
      float4 x0=vp[0], x1=vp[1], x2=vp[2], x3=vp[3];
      vr[0]=x0.x; vr[1]=x0.y; vr[2]=x0.z; vr[3]=x0.w;
      vr[4]=x1.x; vr[5]=x1.y; vr[6]=x1.z; vr[7]=x1.w;
      vr[8]=x2.x; vr[9]=x2.y; vr[10]=x2.z; vr[11]=x2.w;
      vr[12]=x3.x; vr[13]=x3.y; vr[14]=x3.z; vr[15]=x3.w;
    } else {
      const float* vb = v + (size_t)bh*16384 + s;
      #pragma unroll
      for(int dd=0;dd<16;dd++) vr[dd] = vb[dd*1024];
    }
    const float p0c = sc0[c], p1c = sc1[c];
    #pragma unroll
    for(int dd=0;dd<16;dd++){ acc0[dd]=fmaf(p0c,vr[dd],acc0[dd]); acc1[dd]=fmaf(p1c,vr[dd],acc1[dd]); }
  }
  #pragma unroll
  for(int dd=0;dd<16;dd++){ acc0[dd]=wave_sum(acc0[dd]); acc1[dd]=wave_sum(acc1[dd]); }
  {
    float val = 0.f;
    #pragma unroll
    for(int dd=0;dd<16;dd++){
      val = (lane==dd)    ? acc0[dd] : val;
      val = (lane==16+dd) ? acc1[dd] : val;
    }
    if (lane < 32) msg0[(size_t)(gq0 + (lane>>4))*16 + (lane&15)] = val;
  }

  // ---- top-16 per query ----
  const int c0 = top16_reg(sc0, lane);
  if (lane < 16) topk0[(size_t)gq0*16 + lane] = c0;
  const int c1 = top16_reg(sc1, lane);
  if (lane < 16) topk0[(size_t)(gq0+1)*16 + lane] = c1;
}

// ---------------- mid: K=64 gathered children, 4 queries/group, top-8 -------
// 1 group/wave, wave-private LDS, no barriers. TOK: lane=key loads its K row
// into regs + V row -> LDS. Top-8: 4 parallel 16-lane groups (g handles t=g).
template<bool TOK>
__global__ __launch_bounds__(256) void k_mid(
    const float* __restrict__ q, const float* __restrict__ k, const float* __restrict__ v,
    const float* __restrict__ ktok, const float* __restrict__ vtok,
    const int* __restrict__ topk0, float* __restrict__ msg1, int* __restrict__ topk1)
{
  __shared__ float s_v[4][16][66];
  __shared__ float s_e[4][4][65];
  __shared__ float s_k[TOK?1:4][16][66];
  const int tid = threadIdx.x, wid = tid>>6, lane = tid&63;
  const int slot = __builtin_amdgcn_readfirstlane(blockIdx.x*4 + wid);
  const int l = slot & 1023, bh = slot >> 10;
  const int gy = l>>5, gx = l&31;
  const float* qb = q + (size_t)bh*65536;

  float kv[16];
  if constexpr (TOK){
    const int w = lane>>2, c = lane&3;
    const int widx = topk0[(size_t)slot*16 + w];
    const int pos = (2*(widx>>5) + (c>>1))*64 + 2*(widx&31) + (c&1);
    const float4* kp = (const float4*)(ktok + ((size_t)bh*4096 + pos)*16);
    float4 x0=kp[0], x1=kp[1], x2=kp[2], x3=kp[3];
    kv[0]=x0.x; kv[1]=x0.y; kv[2]=x0.z; kv[3]=x0.w;
    kv[4]=x1.x; kv[5]=x1.y; kv[6]=x1.z; kv[7]=x1.w;
    kv[8]=x2.x; kv[9]=x2.y; kv[10]=x2.z; kv[11]=x2.w;
    kv[12]=x3.x; kv[13]=x3.y; kv[14]=x3.z; kv[15]=x3.w;
    const float4* vp = (const float4*)(vtok + ((size_t)bh*4096 + pos)*16);
    float4 y0=vp[0], y1=vp[1], y2=vp[2], y3=vp[3];
    s_v[wid][0][lane]=y0.x;  s_v[wid][1][lane]=y0.y;  s_v[wid][2][lane]=y0.z;  s_v[wid][3][lane]=y0.w;
    s_v[wid][4][lane]=y1.x;  s_v[wid][5][lane]=y1.y;  s_v[wid][6][lane]=y1.z;  s_v[wid][7][lane]=y1.w;
    s_v[wid][8][lane]=y2.x;  s_v[wid][9][lane]=y2.y;  s_v[wid][10][lane]=y2.z; s_v[wid][11][lane]=y2.w;
    s_v[wid][12][lane]=y3.x; s_v[wid][13][lane]=y3.y; s_v[wid][14][lane]=y3.z; s_v[wid][15][lane]=y3.w;
  } else {
    const int kvsel = lane>>5, rr = lane&31, w = rr>>1, cy = rr&1;
    const int widx = topk0[(size_t)slot*16 + w];
    const int base = (2*(widx>>5) + cy)*64 + 2*(widx&31);
    const float* src = (kvsel ? v : k) + (size_t)bh*65536;
    float* dst = kvsel ? &s_v[wid][0][0] : &s_k[wid][0][0];
    const int key0 = w*4 + cy*2;
    #pragma unroll
    for(int dd=0;dd<16;dd++){
      const float2 f2 = *(const float2*)(src + dd*4096 + base);
      *(float2*)(dst + dd*66 + key0) = f2;
    }
    #pragma unroll
    for(int dd=0;dd<16;dd++) kv[dd] = s_k[wid][dd][lane];
  }

  // ---- scores + softmax (lane = gathered key) ----
  #pragma unroll
  for(int t=0;t<4;t++){
    const int qp = (2*gy + (t>>1))*64 + 2*gx + (t&1);
    float a = 0.f;
    #pragma unroll
    for(int dd=0;dd<16;dd++) a = fmaf(qb[dd*4096 + qp], kv[dd], a);
    a *= 0.25f;
    const float m = wave_max(a);
    const float e = __expf(a - m);
    const float s = wave_sum(e);
    s_e[wid][t][lane] = e / s;
  }

  // ---- top-8: group g (16 lanes) handles t=g; lane j owns keys j*4+e ----
  const int g = lane>>4, j = lane&15;
  {
    const int wj_ = topk0[(size_t)slot*16 + j];
    const int tyj = wj_>>5, txj = wj_&31;
    int posj[4];
    #pragma unroll
    for(int e=0;e<4;e++) posj[e] = (2*tyj + (e>>1))*64 + 2*txj + (e&1);
    float ev[4];
    #pragma unroll
    for(int e=0;e<4;e++) ev[e] = s_e[wid][g][j*4+e];
    int cap = 0;
    for(int r=0;r<8;r++){
      float lv = ev[0]; int le = 0;
      #pragma unroll
      for(int e=1;e<4;e++) if (ev[e] > lv){ lv=ev[e]; le=e; }   // tie->lowest e
      float gv = lv; int gk = j*4 + le;
      #pragma unroll
      for(int o=8;o>0;o>>=1){
        float ov = __shfl_xor(gv,o,64); int ok = __shfl_xor(gk,o,64);
        if (ov > gv || (ov == gv && ok < gk)){ gv=ov; gk=ok; }
      }
      const int estar = gk&3, h = gk>>2;
      int seli = posj[0];
      seli = (estar==1) ? posj[1] : seli;
      seli = (estar==2) ? posj[2] : seli;
      seli = (estar==3) ? posj[3] : seli;
      const int wpos = __shfl(seli, (lane & 48) | h, 64);
      #pragma unroll
      for(int e=0;e<4;e++) if (j==h && e==estar) ev[e] = -1e30f;
      if (j == r) cap = wpos;
    }
    if (j < 8){
      const int sp = (2*gy + (g>>1))*64 + 2*gx + (g&1);
      topk1[((size_t)bh*4096 + sp)*8 + j] = cap;
    }
  }

  // ---- msg1 = A @ gathered V: lane = (t,dd) ----
  {
    const int t = lane>>4, dd = lane&15;
    float a = 0.f;
    #pragma unroll
    for(int kk=0;kk<64;kk++) a = fmaf(s_e[wid][t][kk], s_v[wid][dd][kk], a);
    const int sp = (2*gy + (t>>1))*64 + 2*gx + (t&1);
    msg1[((size_t)bh*4096 + sp)*16 + dd] = a;
  }
}

// ---------------- fine: K=32 gathered children + fused combine --------------
// 1 group/wave, wave-private LDS, no barriers. TOK: lanes<32 load K rows,
// lanes>=32 load V rows (4x dwordx4 each), both -> LDS.
template<bool TOK>
__global__ __launch_bounds__(256) void k_fine(
    const float* __restrict__ q, const float* __restrict__ k, const float* __restrict__ v,
    const float* __restrict__ ktok, const float* __restrict__ vtok,
    const int* __restrict__ topk1, const float* __restrict__ msg0,
    const float* __restrict__ msg1, const float* __restrict__ wvec,
    float* __restrict__ out)
{
  __shared__ float s_k[4][16][34];
  __shared__ float s_v[4][16][34];
  __shared__ float s_q[4][4][17];
  __shared__ float s_e[4][4][33];
  const int tid = threadIdx.x, wid = tid>>6, lane = tid&63;
  const int slot = __builtin_amdgcn_readfirstlane(blockIdx.x*4 + wid);
  const int l = slot & 4095, bh = slot >> 12;
  const int b = bh>>3, h = bh&7;
  const int gy = l>>6, gx = l&63;

  const float* qb = q + (size_t)bh*262144;

  // ---- stage q: lane = (t,dd) ----
  {
    const int t = lane>>4, dd = lane&15;
    const int qp = (2*gy + (t>>1))*128 + 2*gx + (t&1);
    s_q[wid][t][dd] = qb[dd*16384 + qp];
  }
  if constexpr (TOK){
    const int key = lane&31, half = lane>>5;
    const int w = key>>2, c = key&3;
    const int widx = topk1[(size_t)slot*8 + w];
    const int pos = (2*(widx>>6) + (c>>1))*128 + 2*(widx&63) + (c&1);
    const float4* sp4 = (const float4*)((half ? vtok : ktok) + ((size_t)bh*16384 + pos)*16);
    float4 x0=sp4[0], x1=sp4[1], x2=sp4[2], x3=sp4[3];
    float* dst = (half ? &s_v[wid][0][0] : &s_k[wid][0][0]);
    dst[0*34+key]=x0.x;  dst[1*34+key]=x0.y;  dst[2*34+key]=x0.z;  dst[3*34+key]=x0.w;
    dst[4*34+key]=x1.x;  dst[5*34+key]=x1.y;  dst[6*34+key]=x1.z;  dst[7*34+key]=x1.w;
    dst[8*34+key]=x2.x;  dst[9*34+key]=x2.y;  dst[10*34+key]=x2.z; dst[11*34+key]=x2.w;
    dst[12*34+key]=x3.x; dst[13*34+key]=x3.y; dst[14*34+key]=x3.z; dst[15*34+key]=x3.w;
  } else {
    const int gs = lane>>1, dh = lane&1;
    const int kvsel = gs>>4, rr = gs&15, w = rr>>1, cy = rr&1;
    const int widx = topk1[(size_t)slot*8 + w];
    const int base = (2*(widx>>6) + cy)*128 + 2*(widx&63);
    const float* src = (kvsel ? v : k) + (size_t)bh*262144;
    float* dst = kvsel ? &s_v[wid][0][0] : &s_k[wid][0][0];
    const int key0 = w*4 + cy*2;
    #pragma unroll
    for(int jj=0;jj<8;jj++){
      const int dd = dh*8 + jj;
      const float2 f2 = *(const float2*)(src + dd*16384 + base);
      *(float2*)(dst + dd*34 + key0) = f2;
    }
  }

  // ---- scores + softmax: lane = (th, key); t = 2*th+tt over 32-lane halves ----
  const int key = lane&31, th = lane>>5;
  float kv[16];
  #pragma unroll
  for(int dd=0;dd<16;dd++) kv[dd] = s_k[wid][dd][key];
  #pragma unroll
  for(int tt=0;tt<2;tt++){
    const int t = th*2 + tt;
    float a = 0.f;
    #pragma unroll
    for(int dd=0;dd<16;dd++) a = fmaf(s_q[wid][t][dd], kv[dd], a);
    a *= 0.25f;
    const float m = half_max(a);
    const float e = __expf(a - m);
    const float s = half_sum(e);
    s_e[wid][t][key] = e / s;
  }

  // ---- weight softmax ----
  const float w0i = wvec[0], w1i = wvec[1], w2i = wvec[2];
  const float wm = fmaxf(w0i, fmaxf(w1i, w2i));
  float e0 = __expf(w0i-wm), e1 = __expf(w1i-wm), e2 = __expf(w2i-wm);
  const float wsum = e0+e1+e2;
  e0/=wsum; e1/=wsum; e2/=wsum;

  // ---- msg2 + combine: lane = (t,dd) ----
  const int t2 = lane>>4, dd2 = lane&15;
  float a = 0.f;
  #pragma unroll
  for(int kk=0;kk<32;kk++) a = fmaf(s_e[wid][t2][kk], s_v[wid][dd2][kk], a);

  const int cl = (gy>>1)*32 + (gx>>1);
  const float m0 = msg0[((size_t)bh*1024 + cl)*16 + dd2];
  const float m1 = msg1[(size_t)slot*16 + dd2];
  const int pp = (2*gy + (t2>>1))*128 + 2*gx + (t2&1);
  out[(((size_t)b*16384 + pp)*8 + h)*16 + dd2] = e0*m0 + e1*m1 + e2*a;
}

extern "C" void kernel_launch(void* const* d_in, const int* in_sizes, int n_in,
                              void* d_out, int out_size, void* d_ws, size_t ws_size,
                              hipStream_t stream) {
  const float* q0 = (const float*)d_in[0];
  const float* q1 = (const float*)d_in[1];
  const float* q2 = (const float*)d_in[2];
  const float* k0 = (const float*)d_in[3];
  const float* k1 = (const float*)d_in[4];
  const float* k2 = (const float*)d_in[5];
  const float* v0 = (const float*)d_in[6];
  const float* v1 = (const float*)d_in[7];
  const float* v2 = (const float*)d_in[8];
  const float* wv = (const float*)d_in[9];
  float* out = (float*)d_out;

  // workspace layout
  float* msg0  = (float*)d_ws;                 // 524288 f
  int*   topk0 = (int*)(msg0 + 524288);        // 524288 i
  float* msg1  = (float*)(topk0 + 524288);     // 2097152 f
  int*   topk1 = (int*)(msg1 + 2097152);       // 1048576 i
  float* ktok0 = (float*)(topk1 + 1048576);    // 8388608 f (32MB)
  float* vtok0 = ktok0 + 8388608;              // 8388608 f
  float* ktok1 = vtok0 + 8388608;              // 2097152 f
  float* vtok1 = ktok1 + 2097152;              // 2097152 f
  float* ktok2 = vtok1 + 2097152;              // 524288 f
  float* vtok2 = ktok2 + 524288;               // 524288 f

  const size_t needA = (size_t)(4194304 + 22020096) * 4;  // 104,857,600 B
  const size_t needB = (size_t)(4194304 + 16777216) * 4;  //  83,886,080 B
  const bool tA = ws_size >= needA;
  const bool tB = ws_size >= needB;

  if (tA){
    hipLaunchKernelGGL(k_transpose, dim3(2048), dim3(256), 0, stream, k0, ktok0, 14);
    hipLaunchKernelGGL(k_transpose, dim3(2048), dim3(256), 0, stream, v0, vtok0, 14);
    hipLaunchKernelGGL(k_transpose, dim3(512),  dim3(256), 0, stream, k1, ktok1, 12);
    hipLaunchKernelGGL(k_transpose, dim3(512),  dim3(256), 0, stream, v1, vtok1, 12);
    hipLaunchKernelGGL(k_transpose, dim3(128),  dim3(256), 0, stream, k2, ktok2, 10);
    hipLaunchKernelGGL(k_transpose, dim3(128),  dim3(256), 0, stream, v2, vtok2, 10);
    hipLaunchKernelGGL(k_coarse<true>, dim3(4096),  dim3(256), 0, stream, q2,k2,v2, ktok2,vtok2, msg0, topk0);
    hipLaunchKernelGGL(k_mid<true>,    dim3(8192),  dim3(256), 0, stream, q1,k1,v1, ktok1,vtok1, topk0, msg1, topk1);
    hipLaunchKernelGGL(k_fine<true>,   dim3(32768), dim3(256), 0, stream, q0,k0,v0, ktok0,vtok0, topk1, msg0, msg1, wv, out);
  } else if (tB){
    hipLaunchKernelGGL(k_transpose, dim3(2048), dim3(256), 0, stream, k0, ktok0, 14);
    hipLaunchKernelGGL(k_transpose, dim3(2048), dim3(256), 0, stream, v0, vtok0, 14);
    hipLaunchKernelGGL(k_coarse<false>, dim3(4096),  dim3(256), 0, stream, q2,k2,v2, ktok0,vtok0, msg0, topk0);
    hipLaunchKernelGGL(k_mid<false>,    dim3(8192),  dim3(256), 0, stream, q1,k1,v1, ktok0,vtok0, topk0, msg1, topk1);
    hipLaunchKernelGGL(k_fine<true>,    dim3(32768), dim3(256), 0, stream, q0,k0,v0, ktok0,vtok0, topk1, msg0, msg1, wv, out);
  } else {
    hipLaunchKernelGGL(k_coarse<false>, dim3(4096),  dim3(256), 0, stream, q2,k2,v2, (float*)d_ws,(float*)d_ws, msg0, topk0);
    hipLaunchKernelGGL(k_mid<false>,    dim3(8192),  dim3(256), 0, stream, q1,k1,v1, (float*)d_ws,(float*)d_ws, topk0, msg1, topk1);
    hipLaunchKernelGGL(k_fine<false>,   dim3(32768), dim3(256), 0, stream, q0,k0,v0, (float*)d_ws,(float*)d_ws, topk1, msg0, msg1, wv, out);
  }
}

// Round 5
// 463.770 us; speedup vs baseline: 2.9357x; 1.2407x over previous
//
#include <hip/hip_runtime.h>

// Quadtree attention forward, 3 levels. B=4, C=128, nh=8, d=16, topks=(16,8,8).
// Round 5: coarse top-16 via buffered tournament (local top-4 + ballot argmax,
// short chains), q0/q1 rounds interleaved; merged transpose kernel.

#define DEV static __device__ __forceinline__

DEV float wave_max(float v){
  #pragma unroll
  for(int o=32;o>0;o>>=1) v = fmaxf(v, __shfl_xor(v,o,64));
  return v;
}
DEV float wave_sum(float v){
  #pragma unroll
  for(int o=32;o>0;o>>=1) v += __shfl_xor(v,o,64);
  return v;
}
DEV float half_max(float v){           // aligned 32-lane half
  #pragma unroll
  for(int o=16;o>0;o>>=1) v = fmaxf(v, __shfl_xor(v,o,64));
  return v;
}
DEV float half_sum(float v){
  #pragma unroll
  for(int o=16;o>0;o>>=1) v += __shfl_xor(v,o,64);
  return v;
}
// all-lanes argmax; ties -> lowest idx (matches jax.lax.top_k)
DEV void wave_argmax(float& v, int& idx){
  #pragma unroll
  for(int o=32;o>0;o>>=1){
    float ov = __shfl_xor(v,o,64);
    int   oi = __shfl_xor(idx,o,64);
    if (ov > v || (ov == v && oi < idx)) { v = ov; idx = oi; }
  }
}

// masked local top-4 scan (ascending c, strict > => tie keeps lowest c)
DEV void scan4(const float (&sc)[16], unsigned &rem, float (&tv)[4], int (&tc)[4]){
  #pragma unroll
  for(int t=0;t<4;t++){
    float bv=-1e30f; int bc=0;
    #pragma unroll
    for(int c=0;c<16;c++){
      const bool ok = (((rem>>c)&1u)==0u) && (sc[c] > bv);
      bv = ok ? sc[c] : bv;
      bc = ok ? c : bc;
    }
    tv[t]=bv; tc[t]=bc; rem |= (1u<<bc);
  }
}

// top-16 for two queries, interleaved rounds. Lane holds sc[c] for s=c*64+lane.
// Rank r lands in cap on lane r. Non-destructive on sc.
DEV void top16_pair(const float (&sc0)[16], const float (&sc1)[16], int lane,
                    int &cap0, int &cap1){
  unsigned rem0=0u, rem1=0u;
  float tv0[4], tv1[4]; int tc0[4], tc1[4];
  scan4(sc0, rem0, tv0, tc0);
  scan4(sc1, rem1, tv1, tc1);
  cap0=0; cap1=0;
  #pragma unroll 1
  for(int r=0;r<16;r++){
    const float M0 = wave_max(tv0[0]);
    const float M1 = wave_max(tv1[0]);
    const unsigned long long k0 = __ballot(tv0[0]==M0);
    const unsigned long long k1 = __ballot(tv1[0]==M1);
    int wl0 = (int)__ffsll(k0)-1, ws0;
    int wl1 = (int)__ffsll(k1)-1, ws1;
    if (__popcll(k0)==1){ ws0 = __shfl(tc0[0], wl0)*64 + wl0; }
    else {
      int sel = (tv0[0]==M0) ? (tc0[0]*64+lane) : 0x7fffffff;
      #pragma unroll
      for(int o=32;o>0;o>>=1) sel = min(sel, __shfl_xor(sel,o,64));
      ws0 = sel; wl0 = ws0 & 63;
    }
    if (__popcll(k1)==1){ ws1 = __shfl(tc1[0], wl1)*64 + wl1; }
    else {
      int sel = (tv1[0]==M1) ? (tc1[0]*64+lane) : 0x7fffffff;
      #pragma unroll
      for(int o=32;o>0;o>>=1) sel = min(sel, __shfl_xor(sel,o,64));
      ws1 = sel; wl1 = ws1 & 63;
    }
    cap0 = (lane==r) ? ws0 : cap0;
    cap1 = (lane==r) ? ws1 : cap1;
    if (lane==wl0){
      tv0[0]=tv0[1]; tc0[0]=tc0[1];
      tv0[1]=tv0[2]; tc0[1]=tc0[2];
      tv0[2]=tv0[3]; tc0[2]=tc0[3];
      tv0[3]=-1e30f; tc0[3]=0;
      if (tv0[0] < -1e29f) scan4(sc0, rem0, tv0, tc0);  // rare refill
    }
    if (lane==wl1){
      tv1[0]=tv1[1]; tc1[0]=tc1[1];
      tv1[1]=tv1[2]; tc1[1]=tc1[2];
      tv1[2]=tv1[3]; tc1[2]=tc1[3];
      tv1[3]=-1e30f; tc1[3]=0;
      if (tv1[0] < -1e29f) scan4(sc1, rem1, tv1, tc1);
    }
  }
}

// -------- merged transpose: [bh][16][S] -> [bh*S][16] for all 6 tensors -----
__global__ __launch_bounds__(256) void k_transpose_all(
    const float* __restrict__ k0, const float* __restrict__ v0,
    const float* __restrict__ k1, const float* __restrict__ v1,
    const float* __restrict__ k2, const float* __restrict__ v2,
    float* __restrict__ ktok0, float* __restrict__ vtok0,
    float* __restrict__ ktok1, float* __restrict__ vtok1,
    float* __restrict__ ktok2, float* __restrict__ vtok2)
{
  const int blk = blockIdx.x;
  const float* src; float* dst; int lgS, base;
  if (blk < 4096){ lgS=14; if (blk<2048){src=k0;dst=ktok0;base=0;} else {src=v0;dst=vtok0;base=2048;} }
  else if (blk < 5120){ lgS=12; if (blk<4608){src=k1;dst=ktok1;base=4096;} else {src=v1;dst=vtok1;base=4608;} }
  else { lgS=10; if (blk<5248){src=k2;dst=ktok2;base=5120;} else {src=v2;dst=vtok2;base=5248;} }
  const int id = (blk-base)*256 + threadIdx.x;
  const int s = id & ((1<<lgS)-1), bh = id >> lgS;
  const float* sp = src + ((size_t)bh<<(lgS+4)) + s;
  float r[16];
  #pragma unroll
  for(int dd=0;dd<16;dd++) r[dd] = sp[(size_t)dd<<lgS];
  float4* dp = (float4*)(dst + (size_t)id*16);
  dp[0] = make_float4(r[0],r[1],r[2],r[3]);
  dp[1] = make_float4(r[4],r[5],r[6],r[7]);
  dp[2] = make_float4(r[8],r[9],r[10],r[11]);
  dp[3] = make_float4(r[12],r[13],r[14],r[15]);
}

// ---------------- coarse: full attention over S=1024, top-16 ----------------
// 2 queries/wave, no LDS, no barriers.
template<bool TOK>
__global__ __launch_bounds__(256) void k_coarse(
    const float* __restrict__ q, const float* __restrict__ k, const float* __restrict__ v,
    const float* __restrict__ ktok, const float* __restrict__ vtok,
    float* __restrict__ msg0, int* __restrict__ topk0)
{
  const int tid = threadIdx.x, wid = tid>>6, lane = tid&63;
  const int gq0 = __builtin_amdgcn_readfirstlane((blockIdx.x*4 + wid)*2);
  const int bh = gq0>>10, l0 = gq0&1023;

  const float* qb = q + (size_t)bh*16384;
  float qv0[16], qv1[16];
  #pragma unroll
  for(int dd=0;dd<16;dd++){ qv0[dd]=qb[dd*1024+l0]; qv1[dd]=qb[dd*1024+l0+1]; }

  // ---- pass 1: scores (s = c*64 + lane) ----
  float sc0[16], sc1[16];
  #pragma unroll
  for(int c=0;c<16;c++){
    const int s = c*64 + lane;
    float kr[16];
    if constexpr (TOK){
      const float4* kp = (const float4*)(ktok + ((size_t)bh*1024 + s)*16);
      float4 x0=kp[0], x1=kp[1], x2=kp[2], x3=kp[3];
      kr[0]=x0.x; kr[1]=x0.y; kr[2]=x0.z; kr[3]=x0.w;
      kr[4]=x1.x; kr[5]=x1.y; kr[6]=x1.z; kr[7]=x1.w;
      kr[8]=x2.x; kr[9]=x2.y; kr[10]=x2.z; kr[11]=x2.w;
      kr[12]=x3.x; kr[13]=x3.y; kr[14]=x3.z; kr[15]=x3.w;
    } else {
      const float* kb = k + (size_t)bh*16384 + s;
      #pragma unroll
      for(int dd=0;dd<16;dd++) kr[dd] = kb[dd*1024];
    }
    float a0=0.f, a1=0.f;
    #pragma unroll
    for(int dd=0;dd<16;dd++){ a0=fmaf(qv0[dd],kr[dd],a0); a1=fmaf(qv1[dd],kr[dd],a1); }
    sc0[c]=a0*0.25f; sc1[c]=a1*0.25f;
  }

  // ---- top-16 on scores (exp is monotone; ref ties measure-zero) ----
  int cap0, cap1;
  top16_pair(sc0, sc1, lane, cap0, cap1);
  if (lane < 16){
    topk0[(size_t)gq0*16 + lane]     = cap0;
    topk0[(size_t)(gq0+1)*16 + lane] = cap1;
  }

  // ---- softmax in place ----
  float m0=-1e30f, m1=-1e30f;
  #pragma unroll
  for(int c=0;c<16;c++){ m0=fmaxf(m0,sc0[c]); m1=fmaxf(m1,sc1[c]); }
  m0 = wave_max(m0); m1 = wave_max(m1);
  float s0=0.f, s1=0.f;
  #pragma unroll
  for(int c=0;c<16;c++){ sc0[c]=__expf(sc0[c]-m0); sc1[c]=__expf(sc1[c]-m1); s0+=sc0[c]; s1+=sc1[c]; }
  s0 = wave_sum(s0); s1 = wave_sum(s1);
  const float i0=1.0f/s0, i1=1.0f/s1;
  #pragma unroll
  for(int c=0;c<16;c++){ sc0[c]*=i0; sc1[c]*=i1; }

  // ---- pass 2: AV ----
  float acc0[16], acc1[16];
  #pragma unroll
  for(int dd=0;dd<16;dd++){ acc0[dd]=0.f; acc1[dd]=0.f; }
  #pragma unroll
  for(int c=0;c<16;c++){
    const int s = c*64 + lane;
    float vr[16];
    if constexpr (TOK){
      const float4* vp = (const float4*)(vtok + ((size_t)bh*1024 + s)*16);
      float4 x0=vp[0], x1=vp[1], x2=vp[2], x3=vp[3];
      vr[0]=x0.x; vr[1]=x0.y; vr[2]=x0.z; vr[3]=x0.w;
      vr[4]=x1.x; vr[5]=x1.y; vr[6]=x1.z; vr[7]=x1.w;
      vr[8]=x2.x; vr[9]=x2.y; vr[10]=x2.z; vr[11]=x2.w;
      vr[12]=x3.x; vr[13]=x3.y; vr[14]=x3.z; vr[15]=x3.w;
    } else {
      const float* vb = v + (size_t)bh*16384 + s;
      #pragma unroll
      for(int dd=0;dd<16;dd++) vr[dd] = vb[dd*1024];
    }
    const float p0c = sc0[c], p1c = sc1[c];
    #pragma unroll
    for(int dd=0;dd<16;dd++){ acc0[dd]=fmaf(p0c,vr[dd],acc0[dd]); acc1[dd]=fmaf(p1c,vr[dd],acc1[dd]); }
  }
  #pragma unroll
  for(int dd=0;dd<16;dd++){ acc0[dd]=wave_sum(acc0[dd]); acc1[dd]=wave_sum(acc1[dd]); }
  {
    float val = 0.f;
    #pragma unroll
    for(int dd=0;dd<16;dd++){
      val = (lane==dd)    ? acc0[dd] : val;
      val = (lane==16+dd) ? acc1[dd] : val;
    }
    if (lane < 32) msg0[(size_t)(gq0 + (lane>>4))*16 + (lane&15)] = val;
  }
}

// ---------------- mid: K=64 gathered children, 4 queries/group, top-8 -------
template<bool TOK>
__global__ __launch_bounds__(256) void k_mid(
    const float* __restrict__ q, const float* __restrict__ k, const float* __restrict__ v,
    const float* __restrict__ ktok, const float* __restrict__ vtok,
    const int* __restrict__ topk0, float* __restrict__ msg1, int* __restrict__ topk1)
{
  __shared__ float s_v[4][16][66];
  __shared__ float s_e[4][4][65];
  __shared__ float s_k[TOK?1:4][16][66];
  const int tid = threadIdx.x, wid = tid>>6, lane = tid&63;
  const int slot = __builtin_amdgcn_readfirstlane(blockIdx.x*4 + wid);
  const int l = slot & 1023, bh = slot >> 10;
  const int gy = l>>5, gx = l&31;
  const float* qb = q + (size_t)bh*65536;

  float kv[16];
  if constexpr (TOK){
    const int w = lane>>2, c = lane&3;
    const int widx = topk0[(size_t)slot*16 + w];
    const int pos = (2*(widx>>5) + (c>>1))*64 + 2*(widx&31) + (c&1);
    const float4* kp = (const float4*)(ktok + ((size_t)bh*4096 + pos)*16);
    float4 x0=kp[0], x1=kp[1], x2=kp[2], x3=kp[3];
    kv[0]=x0.x; kv[1]=x0.y; kv[2]=x0.z; kv[3]=x0.w;
    kv[4]=x1.x; kv[5]=x1.y; kv[6]=x1.z; kv[7]=x1.w;
    kv[8]=x2.x; kv[9]=x2.y; kv[10]=x2.z; kv[11]=x2.w;
    kv[12]=x3.x; kv[13]=x3.y; kv[14]=x3.z; kv[15]=x3.w;
    const float4* vp = (const float4*)(vtok + ((size_t)bh*4096 + pos)*16);
    float4 y0=vp[0], y1=vp[1], y2=vp[2], y3=vp[3];
    s_v[wid][0][lane]=y0.x;  s_v[wid][1][lane]=y0.y;  s_v[wid][2][lane]=y0.z;  s_v[wid][3][lane]=y0.w;
    s_v[wid][4][lane]=y1.x;  s_v[wid][5][lane]=y1.y;  s_v[wid][6][lane]=y1.z;  s_v[wid][7][lane]=y1.w;
    s_v[wid][8][lane]=y2.x;  s_v[wid][9][lane]=y2.y;  s_v[wid][10][lane]=y2.z; s_v[wid][11][lane]=y2.w;
    s_v[wid][12][lane]=y3.x; s_v[wid][13][lane]=y3.y; s_v[wid][14][lane]=y3.z; s_v[wid][15][lane]=y3.w;
  } else {
    const int kvsel = lane>>5, rr = lane&31, w = rr>>1, cy = rr&1;
    const int widx = topk0[(size_t)slot*16 + w];
    const int base = (2*(widx>>5) + cy)*64 + 2*(widx&31);
    const float* src = (kvsel ? v : k) + (size_t)bh*65536;
    float* dst = kvsel ? &s_v[wid][0][0] : &s_k[wid][0][0];
    const int key0 = w*4 + cy*2;
    #pragma unroll
    for(int dd=0;dd<16;dd++){
      const float2 f2 = *(const float2*)(src + dd*4096 + base);
      *(float2*)(dst + dd*66 + key0) = f2;
    }
    #pragma unroll
    for(int dd=0;dd<16;dd++) kv[dd] = s_k[wid][dd][lane];
  }

  // ---- scores + softmax (lane = gathered key) ----
  #pragma unroll
  for(int t=0;t<4;t++){
    const int qp = (2*gy + (t>>1))*64 + 2*gx + (t&1);
    float a = 0.f;
    #pragma unroll
    for(int dd=0;dd<16;dd++) a = fmaf(qb[dd*4096 + qp], kv[dd], a);
    a *= 0.25f;
    const float m = wave_max(a);
    const float e = __expf(a - m);
    const float s = wave_sum(e);
    s_e[wid][t][lane] = e / s;
  }

  // ---- top-8: group g (16 lanes) handles t=g; lane j owns keys j*4+e ----
  const int g = lane>>4, j = lane&15;
  {
    const int wj_ = topk0[(size_t)slot*16 + j];
    const int tyj = wj_>>5, txj = wj_&31;
    int posj[4];
    #pragma unroll
    for(int e=0;e<4;e++) posj[e] = (2*tyj + (e>>1))*64 + 2*txj + (e&1);
    float ev[4];
    #pragma unroll
    for(int e=0;e<4;e++) ev[e] = s_e[wid][g][j*4+e];
    int cap = 0;
    for(int r=0;r<8;r++){
      float lv = ev[0]; int le = 0;
      #pragma unroll
      for(int e=1;e<4;e++) if (ev[e] > lv){ lv=ev[e]; le=e; }   // tie->lowest e
      float gv = lv; int gk = j*4 + le;
      #pragma unroll
      for(int o=8;o>0;o>>=1){
        float ov = __shfl_xor(gv,o,64); int ok = __shfl_xor(gk,o,64);
        if (ov > gv || (ov == gv && ok < gk)){ gv=ov; gk=ok; }
      }
      const int estar = gk&3, h = gk>>2;
      int seli = posj[0];
      seli = (estar==1) ? posj[1] : seli;
      seli = (estar==2) ? posj[2] : seli;
      seli = (estar==3) ? posj[3] : seli;
      const int wpos = __shfl(seli, (lane & 48) | h, 64);
      #pragma unroll
      for(int e=0;e<4;e++) if (j==h && e==estar) ev[e] = -1e30f;
      if (j == r) cap = wpos;
    }
    if (j < 8){
      const int sp = (2*gy + (g>>1))*64 + 2*gx + (g&1);
      topk1[((size_t)bh*4096 + sp)*8 + j] = cap;
    }
  }

  // ---- msg1 = A @ gathered V: lane = (t,dd) ----
  {
    const int t = lane>>4, dd = lane&15;
    float a = 0.f;
    #pragma unroll
    for(int kk=0;kk<64;kk++) a = fmaf(s_e[wid][t][kk], s_v[wid][dd][kk], a);
    const int sp = (2*gy + (t>>1))*64 + 2*gx + (t&1);
    msg1[((size_t)bh*4096 + sp)*16 + dd] = a;
  }
}

// ---------------- fine: K=32 gathered children + fused combine --------------
template<bool TOK>
__global__ __launch_bounds__(256) void k_fine(
    const float* __restrict__ q, const float* __restrict__ k, const float* __restrict__ v,
    const float* __restrict__ ktok, const float* __restrict__ vtok,
    const int* __restrict__ topk1, const float* __restrict__ msg0,
    const float* __restrict__ msg1, const float* __restrict__ wvec,
    float* __restrict__ out)
{
  __shared__ float s_k[4][16][34];
  __shared__ float s_v[4][16][34];
  __shared__ float s_q[4][4][17];
  __shared__ float s_e[4][4][33];
  const int tid = threadIdx.x, wid = tid>>6, lane = tid&63;
  const int slot = __builtin_amdgcn_readfirstlane(blockIdx.x*4 + wid);
  const int l = slot & 4095, bh = slot >> 12;
  const int b = bh>>3, h = bh&7;
  const int gy = l>>6, gx = l&63;

  const float* qb = q + (size_t)bh*262144;

  {
    const int t = lane>>4, dd = lane&15;
    const int qp = (2*gy + (t>>1))*128 + 2*gx + (t&1);
    s_q[wid][t][dd] = qb[dd*16384 + qp];
  }
  if constexpr (TOK){
    const int key = lane&31, half = lane>>5;
    const int w = key>>2, c = key&3;
    const int widx = topk1[(size_t)slot*8 + w];
    const int pos = (2*(widx>>6) + (c>>1))*128 + 2*(widx&63) + (c&1);
    const float4* sp4 = (const float4*)((half ? vtok : ktok) + ((size_t)bh*16384 + pos)*16);
    float4 x0=sp4[0], x1=sp4[1], x2=sp4[2], x3=sp4[3];
    float* dst = (half ? &s_v[wid][0][0] : &s_k[wid][0][0]);
    dst[0*34+key]=x0.x;  dst[1*34+key]=x0.y;  dst[2*34+key]=x0.z;  dst[3*34+key]=x0.w;
    dst[4*34+key]=x1.x;  dst[5*34+key]=x1.y;  dst[6*34+key]=x1.z;  dst[7*34+key]=x1.w;
    dst[8*34+key]=x2.x;  dst[9*34+key]=x2.y;  dst[10*34+key]=x2.z; dst[11*34+key]=x2.w;
    dst[12*34+key]=x3.x; dst[13*34+key]=x3.y; dst[14*34+key]=x3.z; dst[15*34+key]=x3.w;
  } else {
    const int gs = lane>>1, dh = lane&1;
    const int kvsel = gs>>4, rr = gs&15, w = rr>>1, cy = rr&1;
    const int widx = topk1[(size_t)slot*8 + w];
    const int base = (2*(widx>>6) + cy)*128 + 2*(widx&63);
    const float* src = (kvsel ? v : k) + (size_t)bh*262144;
    float* dst = kvsel ? &s_v[wid][0][0] : &s_k[wid][0][0];
    const int key0 = w*4 + cy*2;
    #pragma unroll
    for(int jj=0;jj<8;jj++){
      const int dd = dh*8 + jj;
      const float2 f2 = *(const float2*)(src + dd*16384 + base);
      *(float2*)(dst + dd*34 + key0) = f2;
    }
  }

  const int key = lane&31, th = lane>>5;
  float kv[16];
  #pragma unroll
  for(int dd=0;dd<16;dd++) kv[dd] = s_k[wid][dd][key];
  #pragma unroll
  for(int tt=0;tt<2;tt++){
    const int t = th*2 + tt;
    float a = 0.f;
    #pragma unroll
    for(int dd=0;dd<16;dd++) a = fmaf(s_q[wid][t][dd], kv[dd], a);
    a *= 0.25f;
    const float m = half_max(a);
    const float e = __expf(a - m);
    const float s = half_sum(e);
    s_e[wid][t][key] = e / s;
  }

  const float w0i = wvec[0], w1i = wvec[1], w2i = wvec[2];
  const float wm = fmaxf(w0i, fmaxf(w1i, w2i));
  float e0 = __expf(w0i-wm), e1 = __expf(w1i-wm), e2 = __expf(w2i-wm);
  const float wsum = e0+e1+e2;
  e0/=wsum; e1/=wsum; e2/=wsum;

  const int t2 = lane>>4, dd2 = lane&15;
  float a = 0.f;
  #pragma unroll
  for(int kk=0;kk<32;kk++) a = fmaf(s_e[wid][t2][kk], s_v[wid][dd2][kk], a);

  const int cl = (gy>>1)*32 + (gx>>1);
  const float m0 = msg0[((size_t)bh*1024 + cl)*16 + dd2];
  const float m1 = msg1[(size_t)slot*16 + dd2];
  const int pp = (2*gy + (t2>>1))*128 + 2*gx + (t2&1);
  out[(((size_t)b*16384 + pp)*8 + h)*16 + dd2] = e0*m0 + e1*m1 + e2*a;
}

extern "C" void kernel_launch(void* const* d_in, const int* in_sizes, int n_in,
                              void* d_out, int out_size, void* d_ws, size_t ws_size,
                              hipStream_t stream) {
  const float* q0 = (const float*)d_in[0];
  const float* q1 = (const float*)d_in[1];
  const float* q2 = (const float*)d_in[2];
  const float* k0 = (const float*)d_in[3];
  const float* k1 = (const float*)d_in[4];
  const float* k2 = (const float*)d_in[5];
  const float* v0 = (const float*)d_in[6];
  const float* v1 = (const float*)d_in[7];
  const float* v2 = (const float*)d_in[8];
  const float* wv = (const float*)d_in[9];
  float* out = (float*)d_out;

  float* msg0  = (float*)d_ws;                 // 524288 f
  int*   topk0 = (int*)(msg0 + 524288);        // 524288 i
  float* msg1  = (float*)(topk0 + 524288);     // 2097152 f
  int*   topk1 = (int*)(msg1 + 2097152);       // 1048576 i
  float* ktok0 = (float*)(topk1 + 1048576);    // 8388608 f
  float* vtok0 = ktok0 + 8388608;
  float* ktok1 = vtok0 + 8388608;
  float* vtok1 = ktok1 + 2097152;
  float* ktok2 = vtok1 + 2097152;
  float* vtok2 = ktok2 + 524288;

  const size_t needA = (size_t)(4194304 + 22020096) * 4;
  const size_t needB = (size_t)(4194304 + 16777216) * 4;
  const bool tA = ws_size >= needA;
  const bool tB = ws_size >= needB;

  if (tA){
    hipLaunchKernelGGL(k_transpose_all, dim3(5376), dim3(256), 0, stream,
                       k0,v0,k1,v1,k2,v2, ktok0,vtok0,ktok1,vtok1,ktok2,vtok2);
    hipLaunchKernelGGL(k_coarse<true>, dim3(4096),  dim3(256), 0, stream, q2,k2,v2, ktok2,vtok2, msg0, topk0);
    hipLaunchKernelGGL(k_mid<true>,    dim3(8192),  dim3(256), 0, stream, q1,k1,v1, ktok1,vtok1, topk0, msg1, topk1);
    hipLaunchKernelGGL(k_fine<true>,   dim3(32768), dim3(256), 0, stream, q0,k0,v0, ktok0,vtok0, topk1, msg0, msg1, wv, out);
  } else if (tB){
    hipLaunchKernelGGL(k_transpose_all, dim3(4096), dim3(256), 0, stream,
                       k0,v0,k0,v0,k0,v0, ktok0,vtok0,ktok0,vtok0,ktok0,vtok0);
    hipLaunchKernelGGL(k_coarse<false>, dim3(4096),  dim3(256), 0, stream, q2,k2,v2, ktok0,vtok0, msg0, topk0);
    hipLaunchKernelGGL(k_mid<false>,    dim3(8192),  dim3(256), 0, stream, q1,k1,v1, ktok0,vtok0, topk0, msg1, topk1);
    hipLaunchKernelGGL(k_fine<true>,    dim3(32768), dim3(256), 0, stream, q0,k0,v0, ktok0,vtok0, topk1, msg0, msg1, wv, out);
  } else {
    hipLaunchKernelGGL(k_coarse<false>, dim3(4096),  dim3(256), 0, stream, q2,k2,v2, (float*)d_ws,(float*)d_ws, msg0, topk0);
    hipLaunchKernelGGL(k_mid<false>,    dim3(8192),  dim3(256), 0, stream, q1,k1,v1, (float*)d_ws,(float*)d_ws, topk0, msg1, topk1);
    hipLaunchKernelGGL(k_fine<false>,   dim3(32768), dim3(256), 0, stream, q0,k0,v0, (float*)d_ws,(float*)d_ws, topk1, msg0, msg1, wv, out);
  }
}